// Round 2
// baseline (835.193 us; speedup 1.0000x reference)
//
#include <hip/hip_runtime.h>
#include <math.h>

namespace {

constexpr int TT    = 32;    // T
constexpr int DD    = 158;   // D
constexpr int NEWSC = 1024;  // NEWS
constexpr int XPAD  = 1184;  // ws row stride: [price 0..157][pad][news 160..1183]
constexpr int NOFF  = 160;   // news offset inside x row (16B-aligned)
constexpr int DGRU  = 128;
constexpr int HIDN  = 64;    // G*E
constexpr int RPB   = 8;     // rows per block (moe kernel)

// ---------------------------------------------------------------------------
// Kernel A: streaming aggregation. One row per block, high occupancy.
// x[r][0..157]   = price.mean(T)
// x[r][160..1183]= (news*mask).sum(T) / clip(mask.sum(T),1e-6)
// ---------------------------------------------------------------------------
__global__ __launch_bounds__(256)
void agg_kernel(const float* __restrict__ price,
                const float* __restrict__ news,
                const float* __restrict__ mask,
                float* __restrict__ x)
{
  const int r   = blockIdx.x;
  const int tid = threadIdx.x;
  __shared__ float m_s[TT];

  if (tid < TT) m_s[tid] = mask[(size_t)r * TT + tid];
  __syncthreads();

  // every thread computes den redundantly from LDS (broadcast reads, cheap)
  float den = 0.f;
  #pragma unroll
  for (int t = 0; t < TT; ++t) den += m_s[t];
  den = fmaxf(den, 1e-6f);
  const float rden = 1.0f / den;

  // news masked mean: 256 threads x 4 cols, float4 streaming
  {
    const int j0 = tid * 4;
    const float* nb = news + (size_t)r * TT * NEWSC + j0;
    float ax = 0.f, ay = 0.f, az = 0.f, aw = 0.f;
    #pragma unroll
    for (int t = 0; t < TT; ++t) {
      const float  mv = m_s[t];
      const float4 nv = *(const float4*)(nb + (size_t)t * NEWSC);
      ax += mv * nv.x; ay += mv * nv.y; az += mv * nv.z; aw += mv * nv.w;
    }
    float4 o4 = make_float4(ax * rden, ay * rden, az * rden, aw * rden);
    *(float4*)(x + (size_t)r * XPAD + NOFF + j0) = o4;
  }

  // price mean over T
  if (tid < DD) {
    const float* pr = price + (size_t)r * TT * DD + tid;
    float acc = 0.f;
    #pragma unroll
    for (int t = 0; t < TT; ++t) acc += pr[(size_t)t * DD];
    x[(size_t)r * XPAD + tid] = acc * (1.0f / (float)TT);
  }
}

// ---------------------------------------------------------------------------
// Kernel B: router GEMM (x via wave-uniform scalar loads) + gate + top-2 +
// experts + tiny attention + outputs. 8 rows/block, 256 threads.
// ---------------------------------------------------------------------------
__global__ __launch_bounds__(256)
void moe_kernel(const float* __restrict__ x,
                const float* __restrict__ rW,
                const float* __restrict__ rb,
                const float* __restrict__ gW,
                const float* __restrict__ gb,
                const float* __restrict__ eW,
                const float* __restrict__ eb,
                const float* __restrict__ wq,
                const float* __restrict__ wqb,
                const float* __restrict__ wk,
                const float* __restrict__ wkb,
                const float* __restrict__ wv,
                const float* __restrict__ wvb,
                const float* __restrict__ wo,
                const float* __restrict__ wob,
                float* __restrict__ out, int nrows)
{
  __shared__ float hs[RPB][DGRU];      // h = tanh(router)
  __shared__ float part[RPB][DGRU];    // half-1 partials
  __shared__ float hid_s[RPB][HIDN];
  __shared__ float eo_s[RPB][HIDN];
  __shared__ float q_s[RPB][HIDN];
  __shared__ float k_s[RPB][HIDN];
  __shared__ float v_s[RPB][HIDN];
  __shared__ float att_s[RPB][HIDN];

  const int tid  = threadIdx.x;
  const int row0 = blockIdx.x * RPB;

  // ---- router GEMM: acc[r] = sum_i x[r][i] * rW[i][o], split across 2 halves
  {
    const int sh = tid >> 7;
    const int o  = tid & 127;
    float acc[RPB];
    #pragma unroll
    for (int r = 0; r < RPB; ++r) acc[r] = 0.f;

    const float* xb = x + (size_t)row0 * XPAD;

    // segment: logical idx in [b,e); x col = xbase+idx ; rW row = wbase+idx
    auto seg = [&](int b, int e, int xbase, int wbase) {
      int i = b;
      for (; i + 8 <= e; i += 8) {
        float w[8];
        #pragma unroll
        for (int kk = 0; kk < 8; ++kk)
          w[kk] = rW[(size_t)(wbase + i + kk) * DGRU + o];
        #pragma unroll
        for (int r = 0; r < RPB; ++r) {
          const float* xr = xb + (size_t)r * XPAD + xbase + i;  // wave-uniform
          acc[r] += xr[0] * w[0] + xr[1] * w[1] + xr[2] * w[2] + xr[3] * w[3]
                  + xr[4] * w[4] + xr[5] * w[5] + xr[6] * w[6] + xr[7] * w[7];
        }
      }
      for (; i < e; ++i) {
        const float w = rW[(size_t)(wbase + i) * DGRU + o];
        #pragma unroll
        for (int r = 0; r < RPB; ++r)
          acc[r] += xb[(size_t)r * XPAD + xbase + i] * w;
      }
    };

    if (!sh) {
      seg(0, 80, 0, 0);          // price half 0
      seg(0, 512, NOFF, DD);     // news half 0
    } else {
      seg(80, DD, 0, 0);         // price half 1
      seg(512, NEWSC, NOFF, DD); // news half 1
    }

    if (sh) {
      #pragma unroll
      for (int r = 0; r < RPB; ++r) part[r][o] = acc[r];
    }
    __syncthreads();
    if (!sh) {
      const float b = rb[o];
      #pragma unroll
      for (int r = 0; r < RPB; ++r) hs[r][o] = tanhf(acc[r] + part[r][o] + b);
    }
  }
  __syncthreads();

  // ---- per-wave row ownership: wave wgi handles rows wgi and wgi+4 ----
  const int wgi = tid >> 6;
  const int ln  = tid & 63;
  const int ra  = wgi;
  const int rb2 = wgi + 4;

  // ---- hidden = h @ gate_W + gb ----
  float h0 = gb[ln], h1 = gb[ln];
  #pragma unroll 4
  for (int i = 0; i < DGRU; ++i) {
    const float w = gW[(size_t)i * HIDN + ln];   // coalesced, L1-resident
    h0 += hs[ra][i]  * w;
    h1 += hs[rb2][i] * w;
  }
  hid_s[ra][ln]  = h0;
  hid_s[rb2][ln] = h1;
  __syncthreads();

  float* out_pred = out;
  float* out_rw1  = out + (size_t)nrows;
  float* out_hid  = out + (size_t)nrows * 65;
  float* out_idx  = out + (size_t)nrows * 129;
  float* out_rw2  = out + (size_t)nrows * 131;

  // ---- top-2 + routing softmax + outputs (hidden, rw x2, indices) ----
  const float hvv[2] = {h0, h1};
  int   i1v[2], i2v[2];
  float w1v[2], w2v[2];
  #pragma unroll
  for (int rr = 0; rr < 2; ++rr) {
    const int r   = wgi + rr * 4;
    const int row = row0 + r;
    const float hv = hvv[rr];
    // 64-lane all-reduce argmax, lower-index tie-break (matches lax.top_k)
    float bv = hv; int bi = ln;
    #pragma unroll
    for (int off = 32; off >= 1; off >>= 1) {
      const float ov = __shfl_xor(bv, off);
      const int   oi = __shfl_xor(bi, off);
      if (ov > bv || (ov == bv && oi < bi)) { bv = ov; bi = oi; }
    }
    float cv = (ln == bi) ? -1e30f : hv; int ci = ln;
    #pragma unroll
    for (int off = 32; off >= 1; off >>= 1) {
      const float ov = __shfl_xor(cv, off);
      const int   oi = __shfl_xor(ci, off);
      if (ov > cv || (ov == cv && oi < ci)) { cv = ov; ci = oi; }
    }
    // softmax of masked hidden: exp(-1e30 - m1) underflows to 0 exactly
    const float e2 = expf(cv - bv);
    const float zi = 1.0f / (1.0f + e2);
    const float rwl = (ln == bi) ? zi : (ln == ci) ? e2 * zi : 0.0f;
    out_hid[(size_t)row * 64 + ln] = hv;
    out_rw1[(size_t)row * 64 + ln] = rwl;
    out_rw2[(size_t)row * 64 + ln] = rwl;
    if (ln < 2) out_idx[(size_t)row * 2 + ln] = (float)(ln == 0 ? bi : ci);
    i1v[rr] = bi; i2v[rr] = ci; w1v[rr] = zi; w2v[rr] = e2 * zi;
  }

  // ---- expert_out[ge] = sum_j hidden[j] * eW[ge][j] + eb[ge] ----
  {
    float a0 = eb[ln], a1 = eb[ln];
    const float4* ew4 = (const float4*)(eW + (size_t)ln * HIDN);  // 256B/lane
    #pragma unroll
    for (int c = 0; c < 16; ++c) {
      const float4 w4 = ew4[c];
      const int j = c * 4;
      a0 += hid_s[ra][j]  * w4.x + hid_s[ra][j+1]  * w4.y
          + hid_s[ra][j+2]  * w4.z + hid_s[ra][j+3]  * w4.w;
      a1 += hid_s[rb2][j] * w4.x + hid_s[rb2][j+1] * w4.y
          + hid_s[rb2][j+2] * w4.z + hid_s[rb2][j+3] * w4.w;
    }
    eo_s[ra][ln]  = a0;
    eo_s[rb2][ln] = a1;
  }
  __syncthreads();

  // ---- q/k/v: [g][f] = sum_e eo[g][e] * w[g][f][e] + b[g][f] ----
  const int gg = ln >> 3;
  #pragma unroll
  for (int rr = 0; rr < 2; ++rr) {
    const int r = wgi + rr * 4;
    float aq = wqb[ln], ak = wkb[ln], av = wvb[ln];
    #pragma unroll
    for (int ee = 0; ee < 8; ++ee) {
      const float xv = eo_s[r][gg * 8 + ee];
      aq += xv * wq[ln * 8 + ee];
      ak += xv * wk[ln * 8 + ee];
      av += xv * wv[ln * 8 + ee];
    }
    q_s[r][ln] = aq; k_s[r][ln] = ak; v_s[r][ln] = av;
  }
  __syncthreads();

  // ---- tiny attention: per lane (g, e_out) with e_out = hh*2 + d ----
  {
    const int e8  = ln & 7;
    const int dd2 = e8 & 1;
    const int hh  = e8 >> 1;
    const float rs2 = 0.7071067811865476f;       // 1/sqrt(DH)
    #pragma unroll
    for (int rr = 0; rr < 2; ++rr) {
      const int r = wgi + rr * 4;
      float s0 = 0.f, s1 = 0.f;
      #pragma unroll
      for (int h2 = 0; h2 < 4; ++h2) {
        const float qv = q_s[r][gg * 8 + h2 * 2 + dd2];
        s0 += qv * k_s[r][gg * 8 + h2 * 2 + 0];
        s1 += qv * k_s[r][gg * 8 + h2 * 2 + 1];
      }
      s0 *= rs2; s1 *= rs2;
      const float mx = fmaxf(s0, s1);
      const float a0 = expf(s0 - mx);
      const float a1 = expf(s1 - mx);
      const float zi = 1.0f / (a0 + a1);
      att_s[r][ln] = (a0 * v_s[r][gg * 8 + hh * 2 + 0]
                    + a1 * v_s[r][gg * 8 + hh * 2 + 1]) * zi;
    }
  }
  __syncthreads();

  // ---- agg = att @ wo^T + wo_b; predictions = sum(agg * routing) ----
  #pragma unroll
  for (int rr = 0; rr < 2; ++rr) {
    const int r   = wgi + rr * 4;
    const int row = row0 + r;
    float acc = wob[ln];
    #pragma unroll
    for (int ee = 0; ee < 8; ++ee)
      acc += att_s[r][gg * 8 + ee] * wo[ln * 8 + ee];
    const float rwl = (ln == i1v[rr]) ? w1v[rr] : (ln == i2v[rr]) ? w2v[rr] : 0.0f;
    float ps = acc * rwl;
    #pragma unroll
    for (int off = 32; off >= 1; off >>= 1) ps += __shfl_xor(ps, off);
    if (ln == 0) out_pred[row] = ps;
  }
}

} // namespace

extern "C" void kernel_launch(void* const* d_in, const int* in_sizes, int n_in,
                              void* d_out, int out_size, void* d_ws, size_t ws_size,
                              hipStream_t stream) {
  const float* price = (const float*)d_in[0];
  const float* news  = (const float*)d_in[1];
  const float* mask  = (const float*)d_in[2];
  const float* rW    = (const float*)d_in[3];
  const float* rb    = (const float*)d_in[4];
  const float* gW    = (const float*)d_in[5];
  const float* gb    = (const float*)d_in[6];
  const float* eW    = (const float*)d_in[7];
  const float* eb    = (const float*)d_in[8];
  const float* wq    = (const float*)d_in[9];
  const float* wqb   = (const float*)d_in[10];
  const float* wk    = (const float*)d_in[11];
  const float* wkb   = (const float*)d_in[12];
  const float* wv    = (const float*)d_in[13];
  const float* wvb   = (const float*)d_in[14];
  const float* wo    = (const float*)d_in[15];
  const float* wob   = (const float*)d_in[16];
  float* out = (float*)d_out;
  float* xws = (float*)d_ws;                     // 4096*1184*4 = 19.4 MB << ws_size
  const int nrows = in_sizes[2] / TT;            // news_mask is (N, T)
  (void)out_size; (void)n_in; (void)ws_size;

  agg_kernel<<<dim3(nrows), dim3(256), 0, stream>>>(price, news, mask, xws);
  moe_kernel<<<dim3(nrows / RPB), dim3(256), 0, stream>>>(
      xws, rW, rb, gW, gb, eW, eb,
      wq, wqb, wk, wkb, wv, wvb, wo, wob, out, nrows);
}

// Round 4
// 817.914 us; speedup vs baseline: 1.0211x; 1.0211x over previous
//
#include <hip/hip_runtime.h>
#include <math.h>

namespace {

constexpr int TT    = 32;    // T
constexpr int DD    = 158;   // D
constexpr int NEWSC = 1024;  // NEWS
constexpr int NOFF  = 160;   // news offset inside x row (16B-aligned)
constexpr int XP    = 1184;  // x row stride
constexpr int DGRU  = 128;
constexpr int HIDN  = 64;    // G*E
constexpr int RPB   = 4;     // rows per block; wave w owns row w for the tail

__global__ __launch_bounds__(256)
void miga_fused(const float* __restrict__ price,
                const float* __restrict__ news,
                const float* __restrict__ mask,
                const float* __restrict__ rW,
                const float* __restrict__ rb,
                const float* __restrict__ gW,
                const float* __restrict__ gb,
                const float* __restrict__ eW,
                const float* __restrict__ eb,
                const float* __restrict__ wq,
                const float* __restrict__ wqb,
                const float* __restrict__ wk,
                const float* __restrict__ wkb,
                const float* __restrict__ wv,
                const float* __restrict__ wvb,
                const float* __restrict__ wo,
                const float* __restrict__ wob,
                float* __restrict__ out, int nrows)
{
  // 23.6 KB LDS -> 6 blocks/CU (24 waves/CU) during the streaming phase
  __shared__ __align__(16) float xs[RPB][XP];  // [price 0..157][pad][news 160..1183]
  __shared__ float m_s[RPB][TT];
  __shared__ float part[RPB][DGRU];            // router half-1 partials
  __shared__ float hs[RPB][DGRU];              // h = tanh(router)

  const int tid  = threadIdx.x;
  const int row0 = blockIdx.x * RPB;

  // ---- masks -> LDS ----
  if (tid < RPB * TT) {
    const int r = tid >> 5, t = tid & 31;
    m_s[r][t] = mask[(size_t)(row0 + r) * TT + t];
  }
  __syncthreads();

  // ---- price mean over T ----
  if (tid < DD) {
    #pragma unroll
    for (int r = 0; r < RPB; ++r) {
      const float* pr = price + (size_t)(row0 + r) * TT * DD + tid;
      float acc = 0.f;
      #pragma unroll 8
      for (int t = 0; t < TT; ++t) acc += pr[(size_t)t * DD];
      xs[r][tid] = acc * (1.0f / 32.0f);
    }
  }

  // ---- news masked mean: 256 threads x 4 cols, float4 streaming ----
  {
    const int j0 = tid * 4;
    #pragma unroll
    for (int r = 0; r < RPB; ++r) {
      float den = 0.f;
      #pragma unroll
      for (int t = 0; t < TT; ++t) den += m_s[r][t];
      const float rden = 1.0f / fmaxf(den, 1e-6f);
      const float* nb = news + (size_t)(row0 + r) * TT * NEWSC + j0;
      float ax = 0.f, ay = 0.f, az = 0.f, aw = 0.f;
      #pragma unroll 8
      for (int t = 0; t < TT; ++t) {
        const float  mv = m_s[r][t];
        const float4 nv = *(const float4*)(nb + (size_t)t * NEWSC);
        ax += mv * nv.x; ay += mv * nv.y; az += mv * nv.z; aw += mv * nv.w;
      }
      *(float4*)(&xs[r][NOFF + j0]) =
          make_float4(ax * rden, ay * rden, az * rden, aw * rden);
    }
  }
  __syncthreads();

  // ---- router GEMM: h[r][o] = tanh(sum_i x[r][i]*rW[i][o] + rb[o]) ----
  {
    const int sh = tid >> 7;                 // i-range half
    const int o  = tid & 127;
    float acc[RPB];
    #pragma unroll
    for (int r = 0; r < RPB; ++r) acc[r] = 0.f;

    auto seg = [&](int b, int e, int xbase, int wbase) {
      int i = b;
      for (; i + 8 <= e; i += 8) {
        float w[8];
        #pragma unroll
        for (int kk = 0; kk < 8; ++kk)
          w[kk] = rW[(size_t)(wbase + i + kk) * DGRU + o];
        #pragma unroll
        for (int r = 0; r < RPB; ++r) {      // b128 broadcast LDS reads (free)
          const float4 xa = *(const float4*)&xs[r][xbase + i];
          const float4 xb = *(const float4*)&xs[r][xbase + i + 4];
          acc[r] += xa.x * w[0] + xa.y * w[1] + xa.z * w[2] + xa.w * w[3]
                  + xb.x * w[4] + xb.y * w[5] + xb.z * w[6] + xb.w * w[7];
        }
      }
      for (; i < e; ++i) {
        const float w = rW[(size_t)(wbase + i) * DGRU + o];
        #pragma unroll
        for (int r = 0; r < RPB; ++r) acc[r] += xs[r][xbase + i] * w;
      }
    };

    if (!sh) { seg(0, 80, 0, 0);   seg(0, 512, NOFF, DD); }     // 592 i's
    else     { seg(80, DD, 0, 0);  seg(512, NEWSC, NOFF, DD); } // 590 i's

    if (sh) {
      #pragma unroll
      for (int r = 0; r < RPB; ++r) part[r][o] = acc[r];
    }
    __syncthreads();
    if (!sh) {
      const float b = rb[o];
      #pragma unroll
      for (int r = 0; r < RPB; ++r) hs[r][o] = tanhf(acc[r] + part[r][o] + b);
    }
  }
  __syncthreads();

  // ================= tail: wave wvi owns row wvi; in-wave shuffles only =====
  const int wvi = tid >> 6;
  const int ln  = tid & 63;
  const int row = row0 + wvi;

  // ---- hidden = h @ gate_W + gb (hs broadcast reads, gW coalesced) ----
  float hid = gb[ln];
  #pragma unroll 4
  for (int i = 0; i < DGRU; ++i)
    hid += hs[wvi][i] * gW[(size_t)i * HIDN + ln];

  float* out_pred = out;
  float* out_rw1  = out + (size_t)nrows;
  float* out_hid  = out + (size_t)nrows * 65;
  float* out_idx  = out + (size_t)nrows * 129;
  float* out_rw2  = out + (size_t)nrows * 131;

  // ---- top-2 (64-lane argmax butterfly, lower-index tie-break) ----
  float bv = hid; int bi = ln;
  #pragma unroll
  for (int off = 32; off >= 1; off >>= 1) {
    const float ov = __shfl_xor(bv, off);
    const int   oi = __shfl_xor(bi, off);
    if (ov > bv || (ov == bv && oi < bi)) { bv = ov; bi = oi; }
  }
  float cv = (ln == bi) ? -1e30f : hid; int ci = ln;
  #pragma unroll
  for (int off = 32; off >= 1; off >>= 1) {
    const float ov = __shfl_xor(cv, off);
    const int   oi = __shfl_xor(ci, off);
    if (ov > cv || (ov == cv && oi < ci)) { cv = ov; ci = oi; }
  }
  const float e2 = expf(cv - bv);            // exp(-1e30 - m) underflows to 0
  const float zi = 1.0f / (1.0f + e2);
  const float rwl = (ln == bi) ? zi : (ln == ci) ? e2 * zi : 0.0f;
  out_hid[(size_t)row * 64 + ln] = hid;
  out_rw1[(size_t)row * 64 + ln] = rwl;
  out_rw2[(size_t)row * 64 + ln] = rwl;
  if (ln < 2) out_idx[(size_t)row * 2 + ln] = (float)(ln == 0 ? bi : ci);

  // ---- expert_out[ge] = sum_j hidden[j]*eW[ge][j] + eb[ge] (shuffle hid) ----
  float eo = eb[ln];
  {
    const float4* ew4 = (const float4*)(eW + (size_t)ln * HIDN);
    #pragma unroll
    for (int c = 0; c < 16; ++c) {
      const float4 w4 = ew4[c];
      eo += __shfl(hid, c * 4 + 0) * w4.x + __shfl(hid, c * 4 + 1) * w4.y
          + __shfl(hid, c * 4 + 2) * w4.z + __shfl(hid, c * 4 + 3) * w4.w;
    }
  }

  // ---- q/k/v: [g][f] = sum_e eo[g][e]*w[g][f][e] + b ----
  const int gg = ln >> 3;
  float aq = wqb[ln], ak = wkb[ln], av = wvb[ln];
  #pragma unroll
  for (int ee = 0; ee < 8; ++ee) {
    const float xv = __shfl(eo, gg * 8 + ee);
    aq += xv * wq[ln * 8 + ee];
    ak += xv * wk[ln * 8 + ee];
    av += xv * wv[ln * 8 + ee];
  }

  // ---- tiny attention: lane = (g, e_out) with e_out = hh*2 + dd2 ----
  const int e8  = ln & 7;
  const int dd2 = e8 & 1;
  const int hh  = e8 >> 1;
  float s0 = 0.f, s1 = 0.f;
  #pragma unroll
  for (int h2 = 0; h2 < 4; ++h2) {
    const float qv = __shfl(aq, gg * 8 + h2 * 2 + dd2);
    s0 += qv * __shfl(ak, gg * 8 + h2 * 2 + 0);
    s1 += qv * __shfl(ak, gg * 8 + h2 * 2 + 1);
  }
  const float rs2 = 0.7071067811865476f;     // 1/sqrt(DH)
  s0 *= rs2; s1 *= rs2;
  const float mx = fmaxf(s0, s1);
  const float a0 = expf(s0 - mx);
  const float a1 = expf(s1 - mx);
  const float ziA = 1.0f / (a0 + a1);
  const float att = (a0 * __shfl(av, gg * 8 + hh * 2 + 0)
                   + a1 * __shfl(av, gg * 8 + hh * 2 + 1)) * ziA;

  // ---- agg = att @ wo^T + wo_b; predictions = sum(agg * routing) ----
  float acc = wob[ln];
  #pragma unroll
  for (int ee = 0; ee < 8; ++ee)
    acc += __shfl(att, gg * 8 + ee) * wo[ln * 8 + ee];
  float ps = acc * rwl;
  #pragma unroll
  for (int off = 32; off >= 1; off >>= 1) ps += __shfl_xor(ps, off);
  if (ln == 0) out_pred[row] = ps;
}

} // namespace

extern "C" void kernel_launch(void* const* d_in, const int* in_sizes, int n_in,
                              void* d_out, int out_size, void* d_ws, size_t ws_size,
                              hipStream_t stream) {
  const float* price = (const float*)d_in[0];
  const float* news  = (const float*)d_in[1];
  const float* mask  = (const float*)d_in[2];
  const float* rW    = (const float*)d_in[3];
  const float* rb    = (const float*)d_in[4];
  const float* gW    = (const float*)d_in[5];
  const float* gb    = (const float*)d_in[6];
  const float* eW    = (const float*)d_in[7];
  const float* eb    = (const float*)d_in[8];
  const float* wq    = (const float*)d_in[9];
  const float* wqb   = (const float*)d_in[10];
  const float* wk    = (const float*)d_in[11];
  const float* wkb   = (const float*)d_in[12];
  const float* wv    = (const float*)d_in[13];
  const float* wvb   = (const float*)d_in[14];
  const float* wo    = (const float*)d_in[15];
  const float* wob   = (const float*)d_in[16];
  float* out = (float*)d_out;
  const int nrows = in_sizes[2] / TT;          // news_mask is (N, T)
  (void)d_ws; (void)ws_size; (void)out_size; (void)n_in;
  miga_fused<<<dim3(nrows / RPB), dim3(256), 0, stream>>>(
      price, news, mask, rW, rb, gW, gb, eW, eb,
      wq, wqb, wk, wkb, wv, wvb, wo, wob, out, nrows);
}